// Round 11
// baseline (7207.954 us; speedup 1.0000x reference)
//
#include <hip/hip_runtime.h>
#include <hip/hip_bf16.h>
#include <cstdint>
#include <cstddef>

// ---------------- types ----------------
typedef float    f32x4 __attribute__((ext_vector_type(4)));
typedef _Float16 f16x8 __attribute__((ext_vector_type(8)));
typedef _Float16 f16x4 __attribute__((ext_vector_type(4)));

#define BATCH 256
#define SEQT  32
#define S1    9

__device__ __forceinline__ void split2(float a, _Float16& h, _Float16& m) {
    h = (_Float16)a;
    m = (_Float16)(a - (float)h);
}
__device__ __forceinline__ float sigf(float x) { return 1.f / (1.f + expf(-x)); }

__device__ __forceinline__ void gload_lds16(const void* g, void* l) {
    __builtin_amdgcn_global_load_lds(
        (const __attribute__((address_space(1))) unsigned int*)g,
        (__attribute__((address_space(3))) unsigned int*)l, 16, 0, 0);
}

// block-wide (8 waves, 512 thr) sum of (s, ss)
__device__ __forceinline__ void bred8(float& s, float& ss, float* red, int tid) {
    #pragma unroll
    for (int o = 32; o > 0; o >>= 1) {
        s  += __shfl_down(s,  o, 64);
        ss += __shfl_down(ss, o, 64);
    }
    __syncthreads();
    if ((tid & 63) == 0) { red[(tid >> 6) * 2] = s; red[(tid >> 6) * 2 + 1] = ss; }
    __syncthreads();
    s = 0.f; ss = 0.f;
    #pragma unroll
    for (int wv = 0; wv < 8; wv++) { s += red[wv * 2]; ss += red[wv * 2 + 1]; }
}

// =====================================================================
// Weight transpose + 2-way fp16 split: W (K x N) f32 -> H/M (N x K) fp16
// =====================================================================
__global__ void k_transpose_split2(const float* __restrict__ W,
                                   _Float16* __restrict__ H, _Float16* __restrict__ M,
                                   int N, int K) {
    __shared__ float tile[32][33];
    int k0 = blockIdx.x * 32, n0 = blockIdx.y * 32;
    int tx = threadIdx.x, ty = threadIdx.y;
    #pragma unroll
    for (int i = ty; i < 32; i += 8)
        tile[i][tx] = W[(size_t)(k0 + i) * N + (n0 + tx)];
    __syncthreads();
    #pragma unroll
    for (int i = ty; i < 32; i += 8) {
        float a = tile[tx][i];
        _Float16 h, m; split2(a, h, m);
        size_t idx = (size_t)(n0 + i) * K + (k0 + tx);
        H[idx] = h; M[idx] = m;
    }
}

// =====================================================================
// split rows of f32 matrix (row stride s_in) into fp16 planes [R][1024]
// =====================================================================
__global__ void k_split2_rows(const float* __restrict__ src, long s_in,
                              _Float16* __restrict__ H, _Float16* __restrict__ M,
                              int n4) {
    int i = blockIdx.x * 256 + threadIdx.x;
    if (i >= n4) return;
    int e = i << 2;
    int c = e & 1023;
    int r = e >> 10;
    f32x4 v = *(const f32x4*)(src + (size_t)r * s_in + c);
    f16x4 h, m;
    #pragma unroll
    for (int j = 0; j < 4; j++) { _Float16 hh, mm; split2(v[j], hh, mm); h[j] = hh; m[j] = mm; }
    size_t o = ((size_t)r << 10) + c;
    *(f16x4*)(H + o) = h;
    *(f16x4*)(M + o) = m;
}

__global__ void k_copy(const float* __restrict__ src, float* __restrict__ dst, int n4) {
    int i = blockIdx.x * 256 + threadIdx.x;
    if (i < n4) ((f32x4*)dst)[i] = ((const f32x4*)src)[i];
}

// =====================================================================
// step-0 prep: m planes = concat(memory, inp0), mem_ws copy, tanh planes.
// =====================================================================
__global__ void k_prep0(_Float16* __restrict__ Ph, _Float16* __restrict__ Pm,
                        const float* __restrict__ memory, float* __restrict__ mem_ws,
                        _Float16* __restrict__ Th, _Float16* __restrict__ Tm,
                        const float* __restrict__ inp0, long inp_stride) {
    int i = blockIdx.x * 256 + threadIdx.x;
    int e = i << 2;
    int c = e & 1023;
    int r = e >> 10;
    int b = r / 9, s = r - b * 9;
    f32x4 v;
    if (s < 8) {
        size_t mo = (((size_t)(b * 8 + s)) << 10) + c;
        v = *(const f32x4*)(memory + mo);
        *(f32x4*)(mem_ws + mo) = v;
        f16x4 th, tm;
        #pragma unroll
        for (int j = 0; j < 4; j++) {
            float tv = tanhf(v[j]);
            _Float16 hh, mm; split2(tv, hh, mm); th[j] = hh; tm[j] = mm;
        }
        *(f16x4*)(Th + mo) = th;
        *(f16x4*)(Tm + mo) = tm;
    } else {
        v = *(const f32x4*)(inp0 + (size_t)b * inp_stride + c);
    }
    size_t o = ((size_t)r << 10) + c;
    f16x4 h, m;
    #pragma unroll
    for (int j = 0; j < 4; j++) { _Float16 hh, mm; split2(v[j], hh, mm); h[j] = hh; m[j] = mm; }
    *(f16x4*)(Ph + o) = h;
    *(f16x4*)(Pm + o) = m;
}

// =====================================================================
// fp16 split-2 (3-term) MFMA GEMM core (16x16x32), SINGLE-buffered LDS
// (m97-style: stage -> sync -> compute -> sync), 32 KB (BM=128) or
// 24 KB (BM=64) -> 3+ blocks/CU. Block-level overlap hides the drain.
// =====================================================================
template <int BM, int RELU, int WF32, int WPL>
__device__ __forceinline__ void gemm_core(
    const _Float16* __restrict__ APh, const _Float16* __restrict__ APm,
    const _Float16* __restrict__ BPh, const _Float16* __restrict__ BPm,
    const float* __restrict__ bias,
    float* __restrict__ C, long ldc,
    _Float16* __restrict__ Ph, _Float16* __restrict__ Pm,
    int row0, int col0, char* smem, int tid) {
    constexpr int ASLAB = BM * 64;              // bytes per A plane
    constexpr int MM    = BM / 32;
    const int l  = tid & 63;
    const int w  = tid >> 6;
    const int wr = w >> 1, wc = w & 1;

    f32x4 acc[MM][4] = {};

    const int kc  = (l & 3) ^ ((l >> 3) & 3);
    const int r_l = (BM == 128) ? (w * 32 + (l >> 2)) : (w * 16 + (l >> 2));
    const _Float16* aH = APh + (size_t)(row0 + r_l) * 1024 + kc * 8;
    const _Float16* aM = APm + (size_t)(row0 + r_l) * 1024 + kc * 8;
    const _Float16* bH = BPh + (size_t)(col0 + (w * 32 + (l >> 2))) * 1024 + kc * 8;
    const _Float16* bM = BPm + (size_t)(col0 + (w * 32 + (l >> 2))) * 1024 + kc * 8;

    const int kcsel = l >> 4, rsel = l & 15;
    const int swz  = (kcsel ^ ((rsel >> 1) & 3)) * 16;
    const int offA = (wr * (BM / 2) + rsel) * 64 + swz;
    const int offB = (wc * 64 + rsel) * 64 + swz;

#define STG(kk) do {                                             \
        char* dst = smem;                                        \
        if (BM == 128) {                                         \
            char* da = dst + w * 2048;                           \
            gload_lds16(aH + (kk),         da);                  \
            gload_lds16(aH + (kk) + 16384, da + 1024);           \
            gload_lds16(aM + (kk),         da + ASLAB);          \
            gload_lds16(aM + (kk) + 16384, da + ASLAB + 1024);   \
        } else {                                                 \
            char* da = dst + w * 1024;                           \
            gload_lds16(aH + (kk), da);                          \
            gload_lds16(aM + (kk), da + ASLAB);                  \
        }                                                        \
        char* db = dst + 2 * ASLAB + w * 2048;                   \
        gload_lds16(bH + (kk),         db);                      \
        gload_lds16(bH + (kk) + 16384, db + 1024);               \
        gload_lds16(bM + (kk),         db + 8192);               \
        gload_lds16(bM + (kk) + 16384, db + 9216);               \
    } while (0)

#define CMP() do {                                                              \
        const char* sb = smem;                                                  \
        f16x8 ah[MM], am[MM], bh[4], bm[4];                                     \
        _Pragma("unroll")                                                       \
        for (int mm = 0; mm < MM; mm++) {                                       \
            ah[mm] = *(const f16x8*)(sb + offA + mm * 1024);                    \
            am[mm] = *(const f16x8*)(sb + ASLAB + offA + mm * 1024);            \
        }                                                                       \
        _Pragma("unroll")                                                       \
        for (int nn = 0; nn < 4; nn++) {                                        \
            bh[nn] = *(const f16x8*)(sb + 2 * ASLAB + offB + nn * 1024);        \
            bm[nn] = *(const f16x8*)(sb + 2 * ASLAB + 8192 + offB + nn * 1024); \
        }                                                                       \
        _Pragma("unroll")                                                       \
        for (int mm = 0; mm < MM; mm++) {                                       \
            _Pragma("unroll")                                                   \
            for (int nn = 0; nn < 4; nn++) {                                    \
                f32x4 cc = acc[mm][nn];                                         \
                cc = __builtin_amdgcn_mfma_f32_16x16x32_f16(am[mm], bh[nn], cc, 0, 0, 0); \
                cc = __builtin_amdgcn_mfma_f32_16x16x32_f16(ah[mm], bm[nn], cc, 0, 0, 0); \
                cc = __builtin_amdgcn_mfma_f32_16x16x32_f16(ah[mm], bh[nn], cc, 0, 0, 0); \
                acc[mm][nn] = cc;                                               \
            }                                                                   \
        }                                                                       \
    } while (0)

    #pragma unroll 1
    for (int ks = 0; ks < 32; ks++) {
        __syncthreads();          // protect LDS reuse from previous CMP
        STG(ks * 32);
        __syncthreads();          // drain staging before read
        CMP();
    }
#undef STG
#undef CMP

    const int r_in = (l >> 4) * 4;
    const int c_in = l & 15;
    #pragma unroll
    for (int mm = 0; mm < MM; mm++) {
        #pragma unroll
        for (int nn = 0; nn < 4; nn++) {
            int col = col0 + wc * 64 + nn * 16 + c_in;
            float bv = bias[col];
            #pragma unroll
            for (int j = 0; j < 4; j++) {
                int row = row0 + wr * (BM / 2) + mm * 16 + r_in + j;
                float v = acc[mm][nn][j] + bv;
                if (RELU) v = fmaxf(v, 0.f);
                size_t o = (size_t)row * ldc + col;
                if (WF32) C[o] = v;
                if (WPL) {
                    _Float16 h, m; split2(v, h, m);
                    Ph[o] = h; Pm[o] = m;
                }
            }
        }
    }
}

// standalone GEMM kernel (256 threads) with bijective XCD swizzle when n%8==0
template <int BM, int RELU, int WF32, int WPL>
__global__ __launch_bounds__(256) void k_gemm2(
    const _Float16* __restrict__ APh, const _Float16* __restrict__ APm,
    const _Float16* __restrict__ BPh, const _Float16* __restrict__ BPm,
    const float* __restrict__ bias,
    float* __restrict__ C, long ldc,
    _Float16* __restrict__ Ph, _Float16* __restrict__ Pm) {
    __shared__ __align__(16) char smem[BM * 64 * 2 + 16384];
    int wg = blockIdx.y * gridDim.x + blockIdx.x;
    int n  = gridDim.x * gridDim.y;
    if ((n & 7) == 0) {
        int q = n >> 3;
        wg = (wg & 7) * q + (wg >> 3);   // bijective: chunk per XCD
    }
    int bx = wg % gridDim.x, by = wg / gridDim.x;
    gemm_core<BM, RELU, WF32, WPL>(APh, APm, BPh, BPm, bias, C, ldc, Ph, Pm,
                                   bx * BM, by * 128, smem, threadIdx.x);
}

// grouped pair: two independent 128x128-tile GEMMs in one dispatch
struct GemmP {
    const _Float16* APh; const _Float16* APm;
    const _Float16* BPh; const _Float16* BPm;
    const float* bias; float* C; long ldc;
};
__global__ __launch_bounds__(256) void k_gemm_pair(GemmP p0, int n0, int gw0,
                                                   GemmP p1, int gw1) {
    __shared__ __align__(16) char smem[32768];
    int id = blockIdx.x;
    if (id < n0) {
        gemm_core<128, 0, 1, 0>(p0.APh, p0.APm, p0.BPh, p0.BPm, p0.bias, p0.C, p0.ldc,
                                nullptr, nullptr, (id % gw0) * 128, (id / gw0) * 128,
                                smem, threadIdx.x);
    } else {
        id -= n0;
        gemm_core<128, 0, 1, 0>(p1.APh, p1.APm, p1.BPh, p1.BPm, p1.bias, p1.C, p1.ldc,
                                nullptr, nullptr, (id % gw1) * 128, (id / gw1) * 128,
                                smem, threadIdx.x);
    }
}

// =====================================================================
// FUSED: LN(qkv) + attention (2 heads/iter) + m = LN(m + att).
// m is planes-only (Ph/Pm in & out). grid = BATCH, 512 threads.
// =====================================================================
__global__ __launch_bounds__(512) void k_ln_attn_addln1(
    const float* __restrict__ qkv,
    const float* __restrict__ gq, const float* __restrict__ bq,   // [9][3072]
    _Float16* __restrict__ Ph, _Float16* __restrict__ Pm,
    const float* __restrict__ g1, const float* __restrict__ b1) { // [9216]
    __shared__ float att_out[9][1024];
    __shared__ float qs[2][9][128], ks[2][9][128], vs[2][9][128];
    __shared__ float att[2][9][12];
    __shared__ float red[16];
    const int tid = threadIdx.x;
    const int b   = blockIdx.x;
    const float* Q = qkv + (size_t)b * 27648;

    float s = 0.f, ss = 0.f;
    for (int i = tid * 4; i < 27648; i += 2048) {
        f32x4 v = *(const f32x4*)(Q + i);
        s  += v[0] + v[1] + v[2] + v[3];
        ss += v[0]*v[0] + v[1]*v[1] + v[2]*v[2] + v[3]*v[3];
    }
    bred8(s, ss, red, tid);
    const float invn = 1.f / 27648.f;
    const float mean = s * invn;
    const float rstd = rsqrtf(ss * invn - mean * mean + 1e-5f);
    const float scale = 0.08838834764831845f;  // 128^-0.5

    for (int h0 = 0; h0 < 8; h0 += 2) {
        __syncthreads();
        for (int i = tid; i < 2304; i += 512) {
            int hh = i / 1152, rem = i - hh * 1152;
            int sx = rem >> 7, d = rem & 127;
            int gb = sx * 3072 + (h0 + hh) * 384 + d;
            qs[hh][sx][d] = ((Q[gb]       - mean) * rstd * gq[gb]       + bq[gb])       * scale;
            ks[hh][sx][d] =  (Q[gb + 128] - mean) * rstd * gq[gb + 128] + bq[gb + 128];
            vs[hh][sx][d] =  (Q[gb + 256] - mean) * rstd * gq[gb + 256] + bq[gb + 256];
        }
        __syncthreads();
        for (int g = tid >> 2; g < 162; g += 128) {
            int hh = g / 81, r = g - hh * 81;
            int qi = r / 9, ki = r - qi * 9;
            const float* qp = qs[hh][qi];
            const float* kp = ks[hh][ki];
            float s4 = 0.f;
            for (int d = tid & 3; d < 128; d += 4) s4 += qp[d] * kp[d];
            s4 += __shfl_xor(s4, 1);
            s4 += __shfl_xor(s4, 2);
            if ((tid & 3) == 0) att[hh][qi][ki] = s4;
        }
        __syncthreads();
        if (tid < 18) {
            int hh = tid / 9, qi = tid - hh * 9;
            float mx = att[hh][qi][0];
            #pragma unroll
            for (int j = 1; j < 9; j++) mx = fmaxf(mx, att[hh][qi][j]);
            float e[9]; float sum = 0.f;
            #pragma unroll
            for (int j = 0; j < 9; j++) { e[j] = expf(att[hh][qi][j] - mx); sum += e[j]; }
            float inv = 1.f / sum;
            #pragma unroll
            for (int j = 0; j < 9; j++) att[hh][qi][j] = e[j] * inv;
        }
        __syncthreads();
        for (int i = tid; i < 2304; i += 512) {
            int hh = i / 1152, rem = i - hh * 1152;
            int sx = rem >> 7, d = rem & 127;
            float ov = 0.f;
            #pragma unroll
            for (int k = 0; k < 9; k++) ov += att[hh][sx][k] * vs[hh][k][d];
            att_out[sx][(h0 + hh) * 128 + d] = ov;
        }
    }
    __syncthreads();

    // ---- m = LN(m + att_out); m reconstructed from planes; emit planes ----
    float* X = &att_out[0][0];
    const size_t pb = (size_t)b * 9216;
    s = 0.f; ss = 0.f;
    for (int i = tid * 4; i < 9216; i += 2048) {
        f16x4 hp = *(const f16x4*)(Ph + pb + i);
        f16x4 mp = *(const f16x4*)(Pm + pb + i);
        f32x4 v;
        #pragma unroll
        for (int j = 0; j < 4; j++) v[j] = (float)hp[j] + (float)mp[j];
        v += *(const f32x4*)(X + i);
        *(f32x4*)(X + i) = v;
        s  += v[0] + v[1] + v[2] + v[3];
        ss += v[0]*v[0] + v[1]*v[1] + v[2]*v[2] + v[3]*v[3];
    }
    bred8(s, ss, red, tid);
    const float invn2 = 1.f / 9216.f;
    const float mean2 = s * invn2;
    const float rstd2 = rsqrtf(ss * invn2 - mean2 * mean2 + 1e-5f);
    for (int i = tid * 4; i < 9216; i += 2048) {
        f32x4 v  = *(const f32x4*)(X + i);
        f32x4 gg = *(const f32x4*)(g1 + i);
        f32x4 bv = *(const f32x4*)(b1 + i);
        v = (v - mean2) * rstd2 * gg + bv;
        f16x4 h, m;
        #pragma unroll
        for (int j = 0; j < 4; j++) { _Float16 hh, mm; split2(v[j], hh, mm); h[j] = hh; m[j] = mm; }
        *(f16x4*)(Ph + pb + i) = h;
        *(f16x4*)(Pm + pb + i) = m;
    }
}

// =====================================================================
// FUSED: m = LN(m + h2); gate; write out_t, mem, next-step planes,
// tanh planes. m planes-only. grid = BATCH, 512 threads.
// =====================================================================
__global__ __launch_bounds__(512) void k_addln2_gate(
    const float* __restrict__ h2,
    const float* __restrict__ g2, const float* __restrict__ b2,
    const float* __restrict__ gmem,
    const float* __restrict__ ginp, long ginp_stride,
    const float* __restrict__ inp_next, long inp_stride,
    const float* __restrict__ fbp, const float* __restrict__ ibp,
    float* __restrict__ mem, float* __restrict__ outp,
    _Float16* __restrict__ Ph, _Float16* __restrict__ Pm,
    _Float16* __restrict__ Th, _Float16* __restrict__ Tm) {
    __shared__ float xs[9216];
    __shared__ float red[16];
    const int tid = threadIdx.x, b = blockIdx.x;
    const size_t pb = (size_t)b * 9216;
    const float* H = h2 + pb;
    float s = 0.f, ss = 0.f;
    for (int i = tid * 4; i < 9216; i += 2048) {
        f16x4 hp = *(const f16x4*)(Ph + pb + i);
        f16x4 mp = *(const f16x4*)(Pm + pb + i);
        f32x4 v;
        #pragma unroll
        for (int j = 0; j < 4; j++) v[j] = (float)hp[j] + (float)mp[j];
        v += *(const f32x4*)(H + i);
        *(f32x4*)(xs + i) = v;
        s  += v[0] + v[1] + v[2] + v[3];
        ss += v[0]*v[0] + v[1]*v[1] + v[2]*v[2] + v[3]*v[3];
    }
    bred8(s, ss, red, tid);
    const float invn = 1.f / 9216.f;
    const float mean = s * invn;
    const float rstd = rsqrtf(ss * invn - mean * mean + 1e-5f);
    const float FB = *fbp, IB = *ibp;

    for (int i = tid * 4; i < 8192; i += 2048) {
        int sx = i >> 10, c = i & 1023;
        size_t gr = (size_t)(b * 8 + sx);
        f32x4 x   = *(const f32x4*)(xs + i);
        f32x4 gm1 = *(const f32x4*)(gmem + gr * 2048 + c);
        f32x4 gm2 = *(const f32x4*)(gmem + gr * 2048 + 1024 + c);
        f32x4 gi1 = *(const f32x4*)(ginp + (size_t)b * ginp_stride + c);
        f32x4 gi2 = *(const f32x4*)(ginp + (size_t)b * ginp_stride + 1024 + c);
        f32x4 old = *(const f32x4*)(mem + gr * 1024 + c);
        f32x4 gg  = *(const f32x4*)(g2 + i);
        f32x4 bb  = *(const f32x4*)(b2 + i);
        f32x4 o;
        f16x4 oh, om, th, tm;
        #pragma unroll
        for (int j = 0; j < 4; j++) {
            float cand = (x[j] - mean) * rstd * gg[j] + bb[j];
            float igv = sigf(gm1[j] + gi1[j] + IB);
            float fgv = sigf(gm2[j] + gi2[j] + FB);
            o[j] = igv * tanhf(cand) + fgv * old[j];
            _Float16 hh, mm; split2(o[j], hh, mm); oh[j] = hh; om[j] = mm;
            float tv = tanhf(o[j]);
            split2(tv, hh, mm); th[j] = hh; tm[j] = mm;
        }
        *(f32x4*)(mem + gr * 1024 + c)         = o;
        *(f32x4*)(outp + (size_t)b * 8192 + i) = o;
        *(f16x4*)(Ph + pb + i) = oh;
        *(f16x4*)(Pm + pb + i) = om;
        size_t to = (size_t)b * 8192 + i;
        *(f16x4*)(Th + to) = th;
        *(f16x4*)(Tm + to) = tm;
    }
    if (inp_next != nullptr && tid < 256) {
        int c = tid * 4;
        f32x4 v = *(const f32x4*)(inp_next + (size_t)b * inp_stride + c);
        f16x4 h, m;
        #pragma unroll
        for (int j = 0; j < 4; j++) { _Float16 hh, mm; split2(v[j], hh, mm); h[j] = hh; m[j] = mm; }
        *(f16x4*)(Ph + pb + 8192 + c) = h;
        *(f16x4*)(Pm + pb + 8192 + c) = m;
    }
}

// =====================================================================
// host launcher
// =====================================================================
extern "C" void kernel_launch(void* const* d_in, const int* in_sizes, int n_in,
                              void* d_out, int out_size, void* d_ws, size_t ws_size,
                              hipStream_t stream) {
    const float* inputs = (const float*)d_in[0];
    const float* memory = (const float*)d_in[1];
    const float* W_qkv  = (const float*)d_in[2];
    const float* b_qkv  = (const float*)d_in[3];
    const float* g_qln  = (const float*)d_in[4];
    const float* b_qln  = (const float*)d_in[5];
    const float* W_mlp  = (const float*)d_in[6];
    const float* b_mlp  = (const float*)d_in[7];
    const float* g_ln1  = (const float*)d_in[8];
    const float* b_ln1  = (const float*)d_in[9];
    const float* g_ln2  = (const float*)d_in[10];
    const float* b_ln2  = (const float*)d_in[11];
    const float* W_in   = (const float*)d_in[12];
    const float* b_in   = (const float*)d_in[13];
    const float* W_ig   = (const float*)d_in[14];
    const float* b_ig   = (const float*)d_in[15];
    const float* W_mg   = (const float*)d_in[16];
    const float* b_mg   = (const float*)d_in[17];
    const float* fb     = (const float*)d_in[18];
    const float* ib     = (const float*)d_in[19];
    float* out = (float*)d_out;

    char* ws = (char*)d_ws;
    size_t off = 0;
    auto alloc = [&](size_t bytes) -> char* {
        char* p = ws + off;
        off += (bytes + 255) & ~(size_t)255;
        return p;
    };
    const size_t NEin = (size_t)1024*1024, NEqkv = (size_t)3072*1024,
                 NEmlp = (size_t)1024*1024, NEig = (size_t)2048*1024, NEmg = (size_t)2048*1024;
    _Float16* WinP  = (_Float16*)alloc(NEin  * 2 * 2);
    _Float16* WqkvP = (_Float16*)alloc(NEqkv * 2 * 2);
    _Float16* WmlpP = (_Float16*)alloc(NEmlp * 2 * 2);
    _Float16* WigP  = (_Float16*)alloc(NEig  * 2 * 2);
    _Float16* WmgP  = (_Float16*)alloc(NEmg  * 2 * 2);

    float*    mem_ws = (float*)alloc((size_t)2048 * 1024 * 4);
    _Float16* mbufP  = (_Float16*)alloc((size_t)2304 * 1024 * 2 * 2);
    float*    qkvbuf = (float*)alloc((size_t)2304 * 3072 * 4);
    float*    gmemb  = (float*)alloc((size_t)2048 * 2048 * 4);
    _Float16* h1P    = (_Float16*)alloc((size_t)2304 * 1024 * 2 * 2);
    float*    h2buf  = (float*)alloc((size_t)2304 * 1024 * 4);
    _Float16* tanhP  = (_Float16*)alloc((size_t)2048 * 1024 * 2 * 2);

    const size_t NEm   = (size_t)2304 * 1024;
    const size_t NEt   = (size_t)2048 * 1024;
    const size_t NEbig = (size_t)8192 * 1024;

    size_t big_bytes = NEbig*2*2 + NEbig*4 + NEbig*2*2 + (size_t)8192*2048*4 + 8192;
    bool big = (ws_size >= off + big_bytes);

    dim3 tb(32, 8);
    k_transpose_split2<<<dim3(32, 32), tb, 0, stream>>>(W_in,  WinP,  WinP + NEin,  1024, 1024);
    k_transpose_split2<<<dim3(32, 96), tb, 0, stream>>>(W_qkv, WqkvP, WqkvP + NEqkv, 3072, 1024);
    k_transpose_split2<<<dim3(32, 32), tb, 0, stream>>>(W_mlp, WmlpP, WmlpP + NEmlp, 1024, 1024);
    k_transpose_split2<<<dim3(32, 64), tb, 0, stream>>>(W_ig,  WigP,  WigP + NEig,  2048, 1024);
    k_transpose_split2<<<dim3(32, 64), tb, 0, stream>>>(W_mg,  WmgP,  WmgP + NEmg,  2048, 1024);

    GemmP pq = { mbufP, mbufP + NEm, WqkvP, WqkvP + NEqkv, b_qkv, qkvbuf, 3072 };
    GemmP pg = { tanhP, tanhP + NEt, WmgP,  WmgP  + NEmg,  b_mg,  gmemb,  2048 };

    if (big) {
        _Float16* inputsP  = (_Float16*)alloc(NEbig * 2 * 2);
        float*    inp_all  = (float*)alloc(NEbig * 4);
        _Float16* inp_allP = (_Float16*)alloc(NEbig * 2 * 2);
        float*    ginp_all = (float*)alloc((size_t)8192 * 2048 * 4);

        k_split2_rows<<<8192, 256, 0, stream>>>(inputs, 1024, inputsP, inputsP + NEbig, 8192 * 256);
        k_gemm2<128,0,1,1><<<dim3(64, 8), 256, 0, stream>>>(inputsP, inputsP + NEbig,
            WinP, WinP + NEin, b_in, inp_all, 1024, inp_allP, inp_allP + NEbig);
        k_gemm2<128,0,1,0><<<dim3(64, 16), 256, 0, stream>>>(inp_allP, inp_allP + NEbig,
            WigP, WigP + NEig, b_ig, ginp_all, 2048, nullptr, nullptr);
        k_prep0<<<2304, 256, 0, stream>>>(mbufP, mbufP + NEm, memory, mem_ws,
                                          tanhP, tanhP + NEt, inp_all, (long)SEQT * 1024);

        for (int t = 0; t < SEQT; t++) {
            k_gemm_pair<<<688, 256, 0, stream>>>(pq, 432, 18, pg, 16);
            k_ln_attn_addln1<<<BATCH, 512, 0, stream>>>(qkvbuf, g_qln, b_qln,
                mbufP, mbufP + NEm, g_ln1, b_ln1);
            k_gemm2<64,1,0,1><<<dim3(36, 8), 256, 0, stream>>>(mbufP, mbufP + NEm,
                WmlpP, WmlpP + NEmlp, b_mlp, nullptr, 1024, h1P, h1P + NEm);
            k_gemm2<64,1,1,0><<<dim3(36, 8), 256, 0, stream>>>(h1P, h1P + NEm,
                WmlpP, WmlpP + NEmlp, b_mlp, h2buf, 1024, nullptr, nullptr);
            const float* inp_next = (t + 1 < SEQT) ? (inp_all + (size_t)(t + 1) * 1024) : nullptr;
            k_addln2_gate<<<BATCH, 512, 0, stream>>>(h2buf, g_ln2, b_ln2,
                gmemb, ginp_all + (size_t)t * 2048, (long)SEQT * 2048,
                inp_next, (long)SEQT * 1024, fb, ib, mem_ws,
                out + (size_t)t * (BATCH * 8192),
                mbufP, mbufP + NEm, tanhP, tanhP + NEt);
        }
    } else {
        const size_t NEs = (size_t)256 * 1024;
        _Float16* stepP  = (_Float16*)alloc(NEs * 2 * 2);
        float*    inpA   = (float*)alloc(NEs * 4);
        _Float16* inpAP  = (_Float16*)alloc(NEs * 2 * 2);
        float*    inpB   = (float*)alloc(NEs * 4);
        _Float16* inpBP  = (_Float16*)alloc(NEs * 2 * 2);
        float*    ginpA  = (float*)alloc((size_t)256 * 2048 * 4);
        float*    ginpB  = (float*)alloc((size_t)256 * 2048 * 4);

        k_split2_rows<<<256, 256, 0, stream>>>(inputs, (long)SEQT * 1024, stepP, stepP + NEs, 256 * 256);
        k_gemm2<128,0,1,1><<<dim3(2, 8), 256, 0, stream>>>(stepP, stepP + NEs,
            WinP, WinP + NEin, b_in, inpA, 1024, inpAP, inpAP + NEs);
        k_gemm2<128,0,1,0><<<dim3(2, 16), 256, 0, stream>>>(inpAP, inpAP + NEs,
            WigP, WigP + NEig, b_ig, ginpA, 2048, nullptr, nullptr);
        k_prep0<<<2304, 256, 0, stream>>>(mbufP, mbufP + NEm, memory, mem_ws,
                                          tanhP, tanhP + NEt, inpA, 1024);

        float *ci = inpA, *cg = ginpA, *ni = inpB, *ng = ginpB;
        _Float16* niP = inpBP;
        _Float16* ciP = inpAP;
        for (int t = 0; t < SEQT; t++) {
            k_gemm_pair<<<688, 256, 0, stream>>>(pq, 432, 18, pg, 16);
            k_ln_attn_addln1<<<BATCH, 512, 0, stream>>>(qkvbuf, g_qln, b_qln,
                mbufP, mbufP + NEm, g_ln1, b_ln1);
            k_gemm2<64,1,0,1><<<dim3(36, 8), 256, 0, stream>>>(mbufP, mbufP + NEm,
                WmlpP, WmlpP + NEmlp, b_mlp, nullptr, 1024, h1P, h1P + NEm);
            k_gemm2<64,1,1,0><<<dim3(36, 8), 256, 0, stream>>>(h1P, h1P + NEm,
                WmlpP, WmlpP + NEmlp, b_mlp, h2buf, 1024, nullptr, nullptr);
            const float* inp_next = nullptr;
            if (t + 1 < SEQT) {
                k_split2_rows<<<256, 256, 0, stream>>>(inputs + (size_t)(t + 1) * 1024,
                    (long)SEQT * 1024, stepP, stepP + NEs, 256 * 256);
                k_gemm2<128,0,1,1><<<dim3(2, 8), 256, 0, stream>>>(stepP, stepP + NEs,
                    WinP, WinP + NEin, b_in, ni, 1024, niP, niP + NEs);
                k_gemm2<128,0,1,0><<<dim3(2, 16), 256, 0, stream>>>(niP, niP + NEs,
                    WigP, WigP + NEig, b_ig, ng, 2048, nullptr, nullptr);
                inp_next = ni;
            }
            k_addln2_gate<<<BATCH, 512, 0, stream>>>(h2buf, g_ln2, b_ln2,
                gmemb, cg, 2048, inp_next, 1024, fb, ib, mem_ws,
                out + (size_t)t * (BATCH * 8192),
                mbufP, mbufP + NEm, tanhP, tanhP + NEt);
            { float* tmp = ci; ci = ni; ni = tmp; }
            { float* tmp = cg; cg = ng; ng = tmp; }
            { _Float16* tmp = ciP; ciP = niP; niP = tmp; }
        }
    }
    k_copy<<<2048, 256, 0, stream>>>(mem_ws, out + (size_t)SEQT * BATCH * 8192, 524288);
}

// Round 12
// 6664.633 us; speedup vs baseline: 1.0815x; 1.0815x over previous
//
#include <hip/hip_runtime.h>
#include <hip/hip_bf16.h>
#include <cstdint>
#include <cstddef>

// ---------------- types ----------------
typedef float    f32x4 __attribute__((ext_vector_type(4)));
typedef _Float16 f16x8 __attribute__((ext_vector_type(8)));
typedef _Float16 f16x4 __attribute__((ext_vector_type(4)));

#define BATCH 256
#define SEQT  32
#define S1    9

__device__ __forceinline__ void split2(float a, _Float16& h, _Float16& m) {
    h = (_Float16)a;
    m = (_Float16)(a - (float)h);
}
__device__ __forceinline__ float sigf(float x) { return 1.f / (1.f + expf(-x)); }

__device__ __forceinline__ void gload_lds16(const void* g, void* l) {
    __builtin_amdgcn_global_load_lds(
        (const __attribute__((address_space(1))) unsigned int*)g,
        (__attribute__((address_space(3))) unsigned int*)l, 16, 0, 0);
}

// bijective XCD swizzle for n % 8 == 0
__device__ __forceinline__ int xcd_swz(int wg, int n) {
    if ((n & 7) != 0) return wg;
    int q = n >> 3;
    return (wg & 7) * q + (wg >> 3);
}

// block-wide (8 waves, 512 thr) sum of (s, ss)
__device__ __forceinline__ void bred8(float& s, float& ss, float* red, int tid) {
    #pragma unroll
    for (int o = 32; o > 0; o >>= 1) {
        s  += __shfl_down(s,  o, 64);
        ss += __shfl_down(ss, o, 64);
    }
    __syncthreads();
    if ((tid & 63) == 0) { red[(tid >> 6) * 2] = s; red[(tid >> 6) * 2 + 1] = ss; }
    __syncthreads();
    s = 0.f; ss = 0.f;
    #pragma unroll
    for (int wv = 0; wv < 8; wv++) { s += red[wv * 2]; ss += red[wv * 2 + 1]; }
}

// =====================================================================
// Weight transpose + 2-way fp16 split: W (K x N) f32 -> H/M (N x K) fp16
// =====================================================================
__global__ void k_transpose_split2(const float* __restrict__ W,
                                   _Float16* __restrict__ H, _Float16* __restrict__ M,
                                   int N, int K) {
    __shared__ float tile[32][33];
    int k0 = blockIdx.x * 32, n0 = blockIdx.y * 32;
    int tx = threadIdx.x, ty = threadIdx.y;
    #pragma unroll
    for (int i = ty; i < 32; i += 8)
        tile[i][tx] = W[(size_t)(k0 + i) * N + (n0 + tx)];
    __syncthreads();
    #pragma unroll
    for (int i = ty; i < 32; i += 8) {
        float a = tile[tx][i];
        _Float16 h, m; split2(a, h, m);
        size_t idx = (size_t)(n0 + i) * K + (k0 + tx);
        H[idx] = h; M[idx] = m;
    }
}

// =====================================================================
// split rows of f32 matrix (row stride s_in) into fp16 planes [R][1024]
// =====================================================================
__global__ void k_split2_rows(const float* __restrict__ src, long s_in,
                              _Float16* __restrict__ H, _Float16* __restrict__ M,
                              int n4) {
    int i = blockIdx.x * 256 + threadIdx.x;
    if (i >= n4) return;
    int e = i << 2;
    int c = e & 1023;
    int r = e >> 10;
    f32x4 v = *(const f32x4*)(src + (size_t)r * s_in + c);
    f16x4 h, m;
    #pragma unroll
    for (int j = 0; j < 4; j++) { _Float16 hh, mm; split2(v[j], hh, mm); h[j] = hh; m[j] = mm; }
    size_t o = ((size_t)r << 10) + c;
    *(f16x4*)(H + o) = h;
    *(f16x4*)(M + o) = m;
}

__global__ void k_copy(const float* __restrict__ src, float* __restrict__ dst, int n4) {
    int i = blockIdx.x * 256 + threadIdx.x;
    if (i < n4) ((f32x4*)dst)[i] = ((const f32x4*)src)[i];
}

// =====================================================================
// step-0 prep: m planes = concat(memory, inp0), mem_ws copy, tanh planes.
// =====================================================================
__global__ void k_prep0(_Float16* __restrict__ Ph, _Float16* __restrict__ Pm,
                        const float* __restrict__ memory, float* __restrict__ mem_ws,
                        _Float16* __restrict__ Th, _Float16* __restrict__ Tm,
                        const float* __restrict__ inp0, long inp_stride) {
    int i = blockIdx.x * 256 + threadIdx.x;
    int e = i << 2;
    int c = e & 1023;
    int r = e >> 10;
    int b = r / 9, s = r - b * 9;
    f32x4 v;
    if (s < 8) {
        size_t mo = (((size_t)(b * 8 + s)) << 10) + c;
        v = *(const f32x4*)(memory + mo);
        *(f32x4*)(mem_ws + mo) = v;
        f16x4 th, tm;
        #pragma unroll
        for (int j = 0; j < 4; j++) {
            float tv = tanhf(v[j]);
            _Float16 hh, mm; split2(tv, hh, mm); th[j] = hh; tm[j] = mm;
        }
        *(f16x4*)(Th + mo) = th;
        *(f16x4*)(Tm + mo) = tm;
    } else {
        v = *(const f32x4*)(inp0 + (size_t)b * inp_stride + c);
    }
    size_t o = ((size_t)r << 10) + c;
    f16x4 h, m;
    #pragma unroll
    for (int j = 0; j < 4; j++) { _Float16 hh, mm; split2(v[j], hh, mm); h[j] = hh; m[j] = mm; }
    *(f16x4*)(Ph + o) = h;
    *(f16x4*)(Pm + o) = m;
}

// =====================================================================
// fp16 split-2 (3-term) MFMA GEMM core (16x16x32), dbuf LDS, 1 barrier/k.
// (EXACT round-8 core — known good, best measured.)
// =====================================================================
template <int BM, int RELU, int WF32, int WPL>
__device__ __forceinline__ void gemm_core(
    const _Float16* __restrict__ APh, const _Float16* __restrict__ APm,
    const _Float16* __restrict__ BPh, const _Float16* __restrict__ BPm,
    const float* __restrict__ bias,
    float* __restrict__ C, long ldc,
    _Float16* __restrict__ Ph, _Float16* __restrict__ Pm,
    int row0, int col0, char* smem, int tid) {
    constexpr int ASLAB = BM * 64;              // bytes per A plane
    constexpr int BUF   = 2 * ASLAB + 16384;    // Ah|Am|Bh(8K)|Bm(8K)
    constexpr int MM    = BM / 32;
    const int l  = tid & 63;
    const int w  = tid >> 6;
    const int wr = w >> 1, wc = w & 1;

    f32x4 acc[MM][4] = {};

    const int kc  = (l & 3) ^ ((l >> 3) & 3);
    const int r_l = (BM == 128) ? (w * 32 + (l >> 2)) : (w * 16 + (l >> 2));
    const _Float16* aH = APh + (size_t)(row0 + r_l) * 1024 + kc * 8;
    const _Float16* aM = APm + (size_t)(row0 + r_l) * 1024 + kc * 8;
    const _Float16* bH = BPh + (size_t)(col0 + (w * 32 + (l >> 2))) * 1024 + kc * 8;
    const _Float16* bM = BPm + (size_t)(col0 + (w * 32 + (l >> 2))) * 1024 + kc * 8;

    const int kcsel = l >> 4, rsel = l & 15;
    const int swz  = (kcsel ^ ((rsel >> 1) & 3)) * 16;
    const int offA = (wr * (BM / 2) + rsel) * 64 + swz;
    const int offB = (wc * 64 + rsel) * 64 + swz;

#define STG(buf, kk) do {                                        \
        char* dst = smem + (buf) * BUF;                          \
        if (BM == 128) {                                         \
            char* da = dst + w * 2048;                           \
            gload_lds16(aH + (kk),         da);                  \
            gload_lds16(aH + (kk) + 16384, da + 1024);           \
            gload_lds16(aM + (kk),         da + ASLAB);          \
            gload_lds16(aM + (kk) + 16384, da + ASLAB + 1024);   \
        } else {                                                 \
            char* da = dst + w * 1024;                           \
            gload_lds16(aH + (kk), da);                          \
            gload_lds16(aM + (kk), da + ASLAB);                  \
        }                                                        \
        char* db = dst + 2 * ASLAB + w * 2048;                   \
        gload_lds16(bH + (kk),         db);                      \
        gload_lds16(bH + (kk) + 16384, db + 1024);               \
        gload_lds16(bM + (kk),         db + 8192);               \
        gload_lds16(bM + (kk) + 16384, db + 9216);               \
    } while (0)

#define CMP(buf) do {                                                           \
        const char* sb = smem + (buf) * BUF;                                    \
        f16x8 ah[MM], am[MM], bh[4], bm[4];                                     \
        _Pragma("unroll")                                                       \
        for (int mm = 0; mm < MM; mm++) {                                       \
            ah[mm] = *(const f16x8*)(sb + offA + mm * 1024);                    \
            am[mm] = *(const f16x8*)(sb + ASLAB + offA + mm * 1024);            \
        }                                                                       \
        _Pragma("unroll")                                                       \
        for (int nn = 0; nn < 4; nn++) {                                        \
            bh[nn] = *(const f16x8*)(sb + 2 * ASLAB + offB + nn * 1024);        \
            bm[nn] = *(const f16x8*)(sb + 2 * ASLAB + 8192 + offB + nn * 1024); \
        }                                                                       \
        _Pragma("unroll")                                                       \
        for (int mm = 0; mm < MM; mm++) {                                       \
            _Pragma("unroll")                                                   \
            for (int nn = 0; nn < 4; nn++) {                                    \
                f32x4 cc = acc[mm][nn];                                         \
                cc = __builtin_amdgcn_mfma_f32_16x16x32_f16(am[mm], bh[nn], cc, 0, 0, 0); \
                cc = __builtin_amdgcn_mfma_f32_16x16x32_f16(ah[mm], bm[nn], cc, 0, 0, 0); \
                cc = __builtin_amdgcn_mfma_f32_16x16x32_f16(ah[mm], bh[nn], cc, 0, 0, 0); \
                acc[mm][nn] = cc;                                               \
            }                                                                   \
        }                                                                       \
    } while (0)

    STG(0, 0);
    __syncthreads();
    int cur = 0;
    #pragma unroll 1
    for (int ks = 0; ks < 31; ks++) {
        STG(cur ^ 1, (ks + 1) * 32);
        CMP(cur);
        __syncthreads();
        cur ^= 1;
    }
    CMP(cur);
#undef STG
#undef CMP

    const int r_in = (l >> 4) * 4;
    const int c_in = l & 15;
    #pragma unroll
    for (int mm = 0; mm < MM; mm++) {
        #pragma unroll
        for (int nn = 0; nn < 4; nn++) {
            int col = col0 + wc * 64 + nn * 16 + c_in;
            float bv = bias[col];
            #pragma unroll
            for (int j = 0; j < 4; j++) {
                int row = row0 + wr * (BM / 2) + mm * 16 + r_in + j;
                float v = acc[mm][nn][j] + bv;
                if (RELU) v = fmaxf(v, 0.f);
                size_t o = (size_t)row * ldc + col;
                if (WF32) C[o] = v;
                if (WPL) {
                    _Float16 h, m; split2(v, h, m);
                    Ph[o] = h; Pm[o] = m;
                }
            }
        }
    }
}

// standalone GEMM kernel (256 threads) + XCD swizzle
template <int BM, int RELU, int WF32, int WPL>
__global__ __launch_bounds__(256) void k_gemm2(
    const _Float16* __restrict__ APh, const _Float16* __restrict__ APm,
    const _Float16* __restrict__ BPh, const _Float16* __restrict__ BPm,
    const float* __restrict__ bias,
    float* __restrict__ C, long ldc,
    _Float16* __restrict__ Ph, _Float16* __restrict__ Pm) {
    __shared__ __align__(16) char smem[(BM * 64 * 2 + 16384) * 2];
    int wg = xcd_swz(blockIdx.y * gridDim.x + blockIdx.x, gridDim.x * gridDim.y);
    int bx = wg % gridDim.x, by = wg / gridDim.x;
    gemm_core<BM, RELU, WF32, WPL>(APh, APm, BPh, BPm, bias, C, ldc, Ph, Pm,
                                   bx * BM, by * 128, smem, threadIdx.x);
}

// grouped pair: two independent 128x128-tile GEMMs in one dispatch (+swizzle)
struct GemmP {
    const _Float16* APh; const _Float16* APm;
    const _Float16* BPh; const _Float16* BPm;
    const float* bias; float* C; long ldc;
};
__global__ __launch_bounds__(256) void k_gemm_pair(GemmP p0, int n0, int gw0,
                                                   GemmP p1, int gw1) {
    __shared__ __align__(16) char smem[65536];
    int id = blockIdx.x;
    if (id < n0) {
        id = xcd_swz(id, n0);
        gemm_core<128, 0, 1, 0>(p0.APh, p0.APm, p0.BPh, p0.BPm, p0.bias, p0.C, p0.ldc,
                                nullptr, nullptr, (id % gw0) * 128, (id / gw0) * 128,
                                smem, threadIdx.x);
    } else {
        id = xcd_swz(id - n0, gridDim.x - n0);
        gemm_core<128, 0, 1, 0>(p1.APh, p1.APm, p1.BPh, p1.BPm, p1.bias, p1.C, p1.ldc,
                                nullptr, nullptr, (id % gw1) * 128, (id / gw1) * 128,
                                smem, threadIdx.x);
    }
}

// =====================================================================
// FUSED: LN(qkv) + attention (2 heads/iter) + m = LN(m + att).
// m is planes-only (Ph/Pm in & out). grid = BATCH, 512 threads.
// =====================================================================
__global__ __launch_bounds__(512) void k_ln_attn_addln1(
    const float* __restrict__ qkv,
    const float* __restrict__ gq, const float* __restrict__ bq,   // [9][3072]
    _Float16* __restrict__ Ph, _Float16* __restrict__ Pm,
    const float* __restrict__ g1, const float* __restrict__ b1) { // [9216]
    __shared__ float att_out[9][1024];
    __shared__ float qs[2][9][128], ks[2][9][128], vs[2][9][128];
    __shared__ float att[2][9][12];
    __shared__ float red[16];
    const int tid = threadIdx.x;
    const int b   = blockIdx.x;
    const float* Q = qkv + (size_t)b * 27648;

    float s = 0.f, ss = 0.f;
    for (int i = tid * 4; i < 27648; i += 2048) {
        f32x4 v = *(const f32x4*)(Q + i);
        s  += v[0] + v[1] + v[2] + v[3];
        ss += v[0]*v[0] + v[1]*v[1] + v[2]*v[2] + v[3]*v[3];
    }
    bred8(s, ss, red, tid);
    const float invn = 1.f / 27648.f;
    const float mean = s * invn;
    const float rstd = rsqrtf(ss * invn - mean * mean + 1e-5f);
    const float scale = 0.08838834764831845f;  // 128^-0.5

    for (int h0 = 0; h0 < 8; h0 += 2) {
        __syncthreads();
        for (int i = tid; i < 2304; i += 512) {
            int hh = i / 1152, rem = i - hh * 1152;
            int sx = rem >> 7, d = rem & 127;
            int gb = sx * 3072 + (h0 + hh) * 384 + d;
            qs[hh][sx][d] = ((Q[gb]       - mean) * rstd * gq[gb]       + bq[gb])       * scale;
            ks[hh][sx][d] =  (Q[gb + 128] - mean) * rstd * gq[gb + 128] + bq[gb + 128];
            vs[hh][sx][d] =  (Q[gb + 256] - mean) * rstd * gq[gb + 256] + bq[gb + 256];
        }
        __syncthreads();
        for (int g = tid >> 2; g < 162; g += 128) {
            int hh = g / 81, r = g - hh * 81;
            int qi = r / 9, ki = r - qi * 9;
            const float* qp = qs[hh][qi];
            const float* kp = ks[hh][ki];
            float s4 = 0.f;
            for (int d = tid & 3; d < 128; d += 4) s4 += qp[d] * kp[d];
            s4 += __shfl_xor(s4, 1);
            s4 += __shfl_xor(s4, 2);
            if ((tid & 3) == 0) att[hh][qi][ki] = s4;
        }
        __syncthreads();
        if (tid < 18) {
            int hh = tid / 9, qi = tid - hh * 9;
            float mx = att[hh][qi][0];
            #pragma unroll
            for (int j = 1; j < 9; j++) mx = fmaxf(mx, att[hh][qi][j]);
            float e[9]; float sum = 0.f;
            #pragma unroll
            for (int j = 0; j < 9; j++) { e[j] = expf(att[hh][qi][j] - mx); sum += e[j]; }
            float inv = 1.f / sum;
            #pragma unroll
            for (int j = 0; j < 9; j++) att[hh][qi][j] = e[j] * inv;
        }
        __syncthreads();
        for (int i = tid; i < 2304; i += 512) {
            int hh = i / 1152, rem = i - hh * 1152;
            int sx = rem >> 7, d = rem & 127;
            float ov = 0.f;
            #pragma unroll
            for (int k = 0; k < 9; k++) ov += att[hh][sx][k] * vs[hh][k][d];
            att_out[sx][(h0 + hh) * 128 + d] = ov;
        }
    }
    __syncthreads();

    // ---- m = LN(m + att_out); m reconstructed from planes; emit planes ----
    float* X = &att_out[0][0];
    const size_t pb = (size_t)b * 9216;
    s = 0.f; ss = 0.f;
    for (int i = tid * 4; i < 9216; i += 2048) {
        f16x4 hp = *(const f16x4*)(Ph + pb + i);
        f16x4 mp = *(const f16x4*)(Pm + pb + i);
        f32x4 v;
        #pragma unroll
        for (int j = 0; j < 4; j++) v[j] = (float)hp[j] + (float)mp[j];
        v += *(const f32x4*)(X + i);
        *(f32x4*)(X + i) = v;
        s  += v[0] + v[1] + v[2] + v[3];
        ss += v[0]*v[0] + v[1]*v[1] + v[2]*v[2] + v[3]*v[3];
    }
    bred8(s, ss, red, tid);
    const float invn2 = 1.f / 9216.f;
    const float mean2 = s * invn2;
    const float rstd2 = rsqrtf(ss * invn2 - mean2 * mean2 + 1e-5f);
    for (int i = tid * 4; i < 9216; i += 2048) {
        f32x4 v  = *(const f32x4*)(X + i);
        f32x4 gg = *(const f32x4*)(g1 + i);
        f32x4 bv = *(const f32x4*)(b1 + i);
        v = (v - mean2) * rstd2 * gg + bv;
        f16x4 h, m;
        #pragma unroll
        for (int j = 0; j < 4; j++) { _Float16 hh, mm; split2(v[j], hh, mm); h[j] = hh; m[j] = mm; }
        *(f16x4*)(Ph + pb + i) = h;
        *(f16x4*)(Pm + pb + i) = m;
    }
}

// =====================================================================
// FUSED: m = LN(m + h2); gate; write out_t, mem, next-step planes,
// tanh planes. m planes-only. grid = BATCH, 512 threads.
// =====================================================================
__global__ __launch_bounds__(512) void k_addln2_gate(
    const float* __restrict__ h2,
    const float* __restrict__ g2, const float* __restrict__ b2,
    const float* __restrict__ gmem,
    const float* __restrict__ ginp, long ginp_stride,
    const float* __restrict__ inp_next, long inp_stride,
    const float* __restrict__ fbp, const float* __restrict__ ibp,
    float* __restrict__ mem, float* __restrict__ outp,
    _Float16* __restrict__ Ph, _Float16* __restrict__ Pm,
    _Float16* __restrict__ Th, _Float16* __restrict__ Tm) {
    __shared__ float xs[9216];
    __shared__ float red[16];
    const int tid = threadIdx.x, b = blockIdx.x;
    const size_t pb = (size_t)b * 9216;
    const float* H = h2 + pb;
    float s = 0.f, ss = 0.f;
    for (int i = tid * 4; i < 9216; i += 2048) {
        f16x4 hp = *(const f16x4*)(Ph + pb + i);
        f16x4 mp = *(const f16x4*)(Pm + pb + i);
        f32x4 v;
        #pragma unroll
        for (int j = 0; j < 4; j++) v[j] = (float)hp[j] + (float)mp[j];
        v += *(const f32x4*)(H + i);
        *(f32x4*)(xs + i) = v;
        s  += v[0] + v[1] + v[2] + v[3];
        ss += v[0]*v[0] + v[1]*v[1] + v[2]*v[2] + v[3]*v[3];
    }
    bred8(s, ss, red, tid);
    const float invn = 1.f / 9216.f;
    const float mean = s * invn;
    const float rstd = rsqrtf(ss * invn - mean * mean + 1e-5f);
    const float FB = *fbp, IB = *ibp;

    for (int i = tid * 4; i < 8192; i += 2048) {
        int sx = i >> 10, c = i & 1023;
        size_t gr = (size_t)(b * 8 + sx);
        f32x4 x   = *(const f32x4*)(xs + i);
        f32x4 gm1 = *(const f32x4*)(gmem + gr * 2048 + c);
        f32x4 gm2 = *(const f32x4*)(gmem + gr * 2048 + 1024 + c);
        f32x4 gi1 = *(const f32x4*)(ginp + (size_t)b * ginp_stride + c);
        f32x4 gi2 = *(const f32x4*)(ginp + (size_t)b * ginp_stride + 1024 + c);
        f32x4 old = *(const f32x4*)(mem + gr * 1024 + c);
        f32x4 gg  = *(const f32x4*)(g2 + i);
        f32x4 bb  = *(const f32x4*)(b2 + i);
        f32x4 o;
        f16x4 oh, om, th, tm;
        #pragma unroll
        for (int j = 0; j < 4; j++) {
            float cand = (x[j] - mean) * rstd * gg[j] + bb[j];
            float igv = sigf(gm1[j] + gi1[j] + IB);
            float fgv = sigf(gm2[j] + gi2[j] + FB);
            o[j] = igv * tanhf(cand) + fgv * old[j];
            _Float16 hh, mm; split2(o[j], hh, mm); oh[j] = hh; om[j] = mm;
            float tv = tanhf(o[j]);
            split2(tv, hh, mm); th[j] = hh; tm[j] = mm;
        }
        *(f32x4*)(mem + gr * 1024 + c)         = o;
        *(f32x4*)(outp + (size_t)b * 8192 + i) = o;
        *(f16x4*)(Ph + pb + i) = oh;
        *(f16x4*)(Pm + pb + i) = om;
        size_t to = (size_t)b * 8192 + i;
        *(f16x4*)(Th + to) = th;
        *(f16x4*)(Tm + to) = tm;
    }
    if (inp_next != nullptr && tid < 256) {
        int c = tid * 4;
        f32x4 v = *(const f32x4*)(inp_next + (size_t)b * inp_stride + c);
        f16x4 h, m;
        #pragma unroll
        for (int j = 0; j < 4; j++) { _Float16 hh, mm; split2(v[j], hh, mm); h[j] = hh; m[j] = mm; }
        *(f16x4*)(Ph + pb + 8192 + c) = h;
        *(f16x4*)(Pm + pb + 8192 + c) = m;
    }
}

// =====================================================================
// host launcher
// =====================================================================
extern "C" void kernel_launch(void* const* d_in, const int* in_sizes, int n_in,
                              void* d_out, int out_size, void* d_ws, size_t ws_size,
                              hipStream_t stream) {
    const float* inputs = (const float*)d_in[0];
    const float* memory = (const float*)d_in[1];
    const float* W_qkv  = (const float*)d_in[2];
    const float* b_qkv  = (const float*)d_in[3];
    const float* g_qln  = (const float*)d_in[4];
    const float* b_qln  = (const float*)d_in[5];
    const float* W_mlp  = (const float*)d_in[6];
    const float* b_mlp  = (const float*)d_in[7];
    const float* g_ln1  = (const float*)d_in[8];
    const float* b_ln1  = (const float*)d_in[9];
    const float* g_ln2  = (const float*)d_in[10];
    const float* b_ln2  = (const float*)d_in[11];
    const float* W_in   = (const float*)d_in[12];
    const float* b_in   = (const float*)d_in[13];
    const float* W_ig   = (const float*)d_in[14];
    const float* b_ig   = (const float*)d_in[15];
    const float* W_mg   = (const float*)d_in[16];
    const float* b_mg   = (const float*)d_in[17];
    const float* fb     = (const float*)d_in[18];
    const float* ib     = (const float*)d_in[19];
    float* out = (float*)d_out;

    char* ws = (char*)d_ws;
    size_t off = 0;
    auto alloc = [&](size_t bytes) -> char* {
        char* p = ws + off;
        off += (bytes + 255) & ~(size_t)255;
        return p;
    };
    const size_t NEin = (size_t)1024*1024, NEqkv = (size_t)3072*1024,
                 NEmlp = (size_t)1024*1024, NEig = (size_t)2048*1024, NEmg = (size_t)2048*1024;
    _Float16* WinP  = (_Float16*)alloc(NEin  * 2 * 2);
    _Float16* WqkvP = (_Float16*)alloc(NEqkv * 2 * 2);
    _Float16* WmlpP = (_Float16*)alloc(NEmlp * 2 * 2);
    _Float16* WigP  = (_Float16*)alloc(NEig  * 2 * 2);
    _Float16* WmgP  = (_Float16*)alloc(NEmg  * 2 * 2);

    float*    mem_ws = (float*)alloc((size_t)2048 * 1024 * 4);
    _Float16* mbufP  = (_Float16*)alloc((size_t)2304 * 1024 * 2 * 2);
    float*    qkvbuf = (float*)alloc((size_t)2304 * 3072 * 4);
    float*    gmemb  = (float*)alloc((size_t)2048 * 2048 * 4);
    _Float16* h1P    = (_Float16*)alloc((size_t)2304 * 1024 * 2 * 2);
    float*    h2buf  = (float*)alloc((size_t)2304 * 1024 * 4);
    _Float16* tanhP  = (_Float16*)alloc((size_t)2048 * 1024 * 2 * 2);

    const size_t NEm   = (size_t)2304 * 1024;
    const size_t NEt   = (size_t)2048 * 1024;
    const size_t NEbig = (size_t)8192 * 1024;

    size_t big_bytes = NEbig*2*2 + NEbig*4 + NEbig*2*2 + (size_t)8192*2048*4 + 8192;
    bool big = (ws_size >= off + big_bytes);

    dim3 tb(32, 8);
    k_transpose_split2<<<dim3(32, 32), tb, 0, stream>>>(W_in,  WinP,  WinP + NEin,  1024, 1024);
    k_transpose_split2<<<dim3(32, 96), tb, 0, stream>>>(W_qkv, WqkvP, WqkvP + NEqkv, 3072, 1024);
    k_transpose_split2<<<dim3(32, 32), tb, 0, stream>>>(W_mlp, WmlpP, WmlpP + NEmlp, 1024, 1024);
    k_transpose_split2<<<dim3(32, 64), tb, 0, stream>>>(W_ig,  WigP,  WigP + NEig,  2048, 1024);
    k_transpose_split2<<<dim3(32, 64), tb, 0, stream>>>(W_mg,  WmgP,  WmgP + NEmg,  2048, 1024);

    GemmP pq = { mbufP, mbufP + NEm, WqkvP, WqkvP + NEqkv, b_qkv, qkvbuf, 3072 };
    GemmP pg = { tanhP, tanhP + NEt, WmgP,  WmgP  + NEmg,  b_mg,  gmemb,  2048 };

    if (big) {
        _Float16* inputsP  = (_Float16*)alloc(NEbig * 2 * 2);
        float*    inp_all  = (float*)alloc(NEbig * 4);
        _Float16* inp_allP = (_Float16*)alloc(NEbig * 2 * 2);
        float*    ginp_all = (float*)alloc((size_t)8192 * 2048 * 4);

        k_split2_rows<<<8192, 256, 0, stream>>>(inputs, 1024, inputsP, inputsP + NEbig, 8192 * 256);
        k_gemm2<128,0,1,1><<<dim3(64, 8), 256, 0, stream>>>(inputsP, inputsP + NEbig,
            WinP, WinP + NEin, b_in, inp_all, 1024, inp_allP, inp_allP + NEbig);
        k_gemm2<128,0,1,0><<<dim3(64, 16), 256, 0, stream>>>(inp_allP, inp_allP + NEbig,
            WigP, WigP + NEig, b_ig, ginp_all, 2048, nullptr, nullptr);
        k_prep0<<<2304, 256, 0, stream>>>(mbufP, mbufP + NEm, memory, mem_ws,
                                          tanhP, tanhP + NEt, inp_all, (long)SEQT * 1024);

        for (int t = 0; t < SEQT; t++) {
            k_gemm_pair<<<688, 256, 0, stream>>>(pq, 432, 18, pg, 16);
            k_ln_attn_addln1<<<BATCH, 512, 0, stream>>>(qkvbuf, g_qln, b_qln,
                mbufP, mbufP + NEm, g_ln1, b_ln1);
            k_gemm2<64,1,0,1><<<dim3(36, 8), 256, 0, stream>>>(mbufP, mbufP + NEm,
                WmlpP, WmlpP + NEmlp, b_mlp, nullptr, 1024, h1P, h1P + NEm);
            k_gemm2<64,1,1,0><<<dim3(36, 8), 256, 0, stream>>>(h1P, h1P + NEm,
                WmlpP, WmlpP + NEmlp, b_mlp, h2buf, 1024, nullptr, nullptr);
            const float* inp_next = (t + 1 < SEQT) ? (inp_all + (size_t)(t + 1) * 1024) : nullptr;
            k_addln2_gate<<<BATCH, 512, 0, stream>>>(h2buf, g_ln2, b_ln2,
                gmemb, ginp_all + (size_t)t * 2048, (long)SEQT * 2048,
                inp_next, (long)SEQT * 1024, fb, ib, mem_ws,
                out + (size_t)t * (BATCH * 8192),
                mbufP, mbufP + NEm, tanhP, tanhP + NEt);
        }
    } else {
        const size_t NEs = (size_t)256 * 1024;
        _Float16* stepP  = (_Float16*)alloc(NEs * 2 * 2);
        float*    inpA   = (float*)alloc(NEs * 4);
        _Float16* inpAP  = (_Float16*)alloc(NEs * 2 * 2);
        float*    inpB   = (float*)alloc(NEs * 4);
        _Float16* inpBP  = (_Float16*)alloc(NEs * 2 * 2);
        float*    ginpA  = (float*)alloc((size_t)256 * 2048 * 4);
        float*    ginpB  = (float*)alloc((size_t)256 * 2048 * 4);

        k_split2_rows<<<256, 256, 0, stream>>>(inputs, (long)SEQT * 1024, stepP, stepP + NEs, 256 * 256);
        k_gemm2<128,0,1,1><<<dim3(2, 8), 256, 0, stream>>>(stepP, stepP + NEs,
            WinP, WinP + NEin, b_in, inpA, 1024, inpAP, inpAP + NEs);
        k_gemm2<128,0,1,0><<<dim3(2, 16), 256, 0, stream>>>(inpAP, inpAP + NEs,
            WigP, WigP + NEig, b_ig, ginpA, 2048, nullptr, nullptr);
        k_prep0<<<2304, 256, 0, stream>>>(mbufP, mbufP + NEm, memory, mem_ws,
                                          tanhP, tanhP + NEt, inpA, 1024);

        float *ci = inpA, *cg = ginpA, *ni = inpB, *ng = ginpB;
        _Float16* niP = inpBP;
        _Float16* ciP = inpAP;
        for (int t = 0; t < SEQT; t++) {
            k_gemm_pair<<<688, 256, 0, stream>>>(pq, 432, 18, pg, 16);
            k_ln_attn_addln1<<<BATCH, 512, 0, stream>>>(qkvbuf, g_qln, b_qln,
                mbufP, mbufP + NEm, g_ln1, b_ln1);
            k_gemm2<64,1,0,1><<<dim3(36, 8), 256, 0, stream>>>(mbufP, mbufP + NEm,
                WmlpP, WmlpP + NEmlp, b_mlp, nullptr, 1024, h1P, h1P + NEm);
            k_gemm2<64,1,1,0><<<dim3(36, 8), 256, 0, stream>>>(h1P, h1P + NEm,
                WmlpP, WmlpP + NEmlp, b_mlp, h2buf, 1024, nullptr, nullptr);
            const float* inp_next = nullptr;
            if (t + 1 < SEQT) {
                k_split2_rows<<<256, 256, 0, stream>>>(inputs + (size_t)(t + 1) * 1024,
                    (long)SEQT * 1024, stepP, stepP + NEs, 256 * 256);
                k_gemm2<128,0,1,1><<<dim3(2, 8), 256, 0, stream>>>(stepP, stepP + NEs,
                    WinP, WinP + NEin, b_in, ni, 1024, niP, niP + NEs);
                k_gemm2<128,0,1,0><<<dim3(2, 16), 256, 0, stream>>>(niP, niP + NEs,
                    WigP, WigP + NEig, b_ig, ng, 2048, nullptr, nullptr);
                inp_next = ni;
            }
            k_addln2_gate<<<BATCH, 512, 0, stream>>>(h2buf, g_ln2, b_ln2,
                gmemb, cg, 2048, inp_next, 1024, fb, ib, mem_ws,
                out + (size_t)t * (BATCH * 8192),
                mbufP, mbufP + NEm, tanhP, tanhP + NEt);
            { float* tmp = ci; ci = ni; ni = tmp; }
            { float* tmp = cg; cg = ng; ng = tmp; }
            { _Float16* tmp = ciP; ciP = niP; niP = tmp; }
        }
    }
    k_copy<<<2048, 256, 0, stream>>>(mem_ws, out + (size_t)SEQT * BATCH * 8192, 524288);
}

// Round 13
// 6379.354 us; speedup vs baseline: 1.1299x; 1.0447x over previous
//
#include <hip/hip_runtime.h>
#include <hip/hip_bf16.h>
#include <cstdint>
#include <cstddef>

// ---------------- types ----------------
typedef float    f32x4 __attribute__((ext_vector_type(4)));
typedef _Float16 f16x8 __attribute__((ext_vector_type(8)));
typedef _Float16 f16x4 __attribute__((ext_vector_type(4)));

#define BATCH 256
#define SEQT  32
#define S1    9

__device__ __forceinline__ void split2(float a, _Float16& h, _Float16& m) {
    h = (_Float16)a;
    m = (_Float16)(a - (float)h);
}
__device__ __forceinline__ float sigf(float x) { return 1.f / (1.f + expf(-x)); }

__device__ __forceinline__ void gload_lds16(const void* g, void* l) {
    __builtin_amdgcn_global_load_lds(
        (const __attribute__((address_space(1))) unsigned int*)g,
        (__attribute__((address_space(3))) unsigned int*)l, 16, 0, 0);
}

// block-wide (8 waves, 512 thr) sum of (s, ss)
__device__ __forceinline__ void bred8(float& s, float& ss, float* red, int tid) {
    #pragma unroll
    for (int o = 32; o > 0; o >>= 1) {
        s  += __shfl_down(s,  o, 64);
        ss += __shfl_down(ss, o, 64);
    }
    __syncthreads();
    if ((tid & 63) == 0) { red[(tid >> 6) * 2] = s; red[(tid >> 6) * 2 + 1] = ss; }
    __syncthreads();
    s = 0.f; ss = 0.f;
    #pragma unroll
    for (int wv = 0; wv < 8; wv++) { s += red[wv * 2]; ss += red[wv * 2 + 1]; }
}

// =====================================================================
// Weight transpose + 2-way fp16 split: W (K x N) f32 -> H/M (N x K) fp16
// =====================================================================
__global__ void k_transpose_split2(const float* __restrict__ W,
                                   _Float16* __restrict__ H, _Float16* __restrict__ M,
                                   int N, int K) {
    __shared__ float tile[32][33];
    int k0 = blockIdx.x * 32, n0 = blockIdx.y * 32;
    int tx = threadIdx.x, ty = threadIdx.y;
    #pragma unroll
    for (int i = ty; i < 32; i += 8)
        tile[i][tx] = W[(size_t)(k0 + i) * N + (n0 + tx)];
    __syncthreads();
    #pragma unroll
    for (int i = ty; i < 32; i += 8) {
        float a = tile[tx][i];
        _Float16 h, m; split2(a, h, m);
        size_t idx = (size_t)(n0 + i) * K + (k0 + tx);
        H[idx] = h; M[idx] = m;
    }
}

// =====================================================================
// split rows of f32 matrix (row stride s_in) into fp16 planes [R][1024]
// =====================================================================
__global__ void k_split2_rows(const float* __restrict__ src, long s_in,
                              _Float16* __restrict__ H, _Float16* __restrict__ M,
                              int n4) {
    int i = blockIdx.x * 256 + threadIdx.x;
    if (i >= n4) return;
    int e = i << 2;
    int c = e & 1023;
    int r = e >> 10;
    f32x4 v = *(const f32x4*)(src + (size_t)r * s_in + c);
    f16x4 h, m;
    #pragma unroll
    for (int j = 0; j < 4; j++) { _Float16 hh, mm; split2(v[j], hh, mm); h[j] = hh; m[j] = mm; }
    size_t o = ((size_t)r << 10) + c;
    *(f16x4*)(H + o) = h;
    *(f16x4*)(M + o) = m;
}

__global__ void k_copy(const float* __restrict__ src, float* __restrict__ dst, int n4) {
    int i = blockIdx.x * 256 + threadIdx.x;
    if (i < n4) ((f32x4*)dst)[i] = ((const f32x4*)src)[i];
}

// =====================================================================
// step-0 prep: m planes = concat(memory, inp0), mem_ws copy, tanh planes.
// =====================================================================
__global__ void k_prep0(_Float16* __restrict__ Ph, _Float16* __restrict__ Pm,
                        const float* __restrict__ memory, float* __restrict__ mem_ws,
                        _Float16* __restrict__ Th, _Float16* __restrict__ Tm,
                        const float* __restrict__ inp0, long inp_stride) {
    int i = blockIdx.x * 256 + threadIdx.x;
    int e = i << 2;
    int c = e & 1023;
    int r = e >> 10;
    int b = r / 9, s = r - b * 9;
    f32x4 v;
    if (s < 8) {
        size_t mo = (((size_t)(b * 8 + s)) << 10) + c;
        v = *(const f32x4*)(memory + mo);
        *(f32x4*)(mem_ws + mo) = v;
        f16x4 th, tm;
        #pragma unroll
        for (int j = 0; j < 4; j++) {
            float tv = tanhf(v[j]);
            _Float16 hh, mm; split2(tv, hh, mm); th[j] = hh; tm[j] = mm;
        }
        *(f16x4*)(Th + mo) = th;
        *(f16x4*)(Tm + mo) = tm;
    } else {
        v = *(const f32x4*)(inp0 + (size_t)b * inp_stride + c);
    }
    size_t o = ((size_t)r << 10) + c;
    f16x4 h, m;
    #pragma unroll
    for (int j = 0; j < 4; j++) { _Float16 hh, mm; split2(v[j], hh, mm); h[j] = hh; m[j] = mm; }
    *(f16x4*)(Ph + o) = h;
    *(f16x4*)(Pm + o) = m;
}

// =====================================================================
// fp16 split-2 (3-term) MFMA GEMM core (16x16x32), dbuf LDS, 1 barrier/k.
// (EXACT round-8 core — known good, best measured.)
// =====================================================================
template <int BM, int RELU, int WF32, int WPL>
__device__ __forceinline__ void gemm_core(
    const _Float16* __restrict__ APh, const _Float16* __restrict__ APm,
    const _Float16* __restrict__ BPh, const _Float16* __restrict__ BPm,
    const float* __restrict__ bias,
    float* __restrict__ C, long ldc,
    _Float16* __restrict__ Ph, _Float16* __restrict__ Pm,
    int row0, int col0, char* smem) {
    constexpr int ASLAB = BM * 64;              // bytes per A plane
    constexpr int BUF   = 2 * ASLAB + 16384;    // Ah|Am|Bh(8K)|Bm(8K)
    constexpr int MM    = BM / 32;
    const int tid = threadIdx.x;
    const int l  = tid & 63;
    const int w  = tid >> 6;
    const int wr = w >> 1, wc = w & 1;

    f32x4 acc[MM][4] = {};

    const int kc  = (l & 3) ^ ((l >> 3) & 3);
    const int r_l = (BM == 128) ? (w * 32 + (l >> 2)) : (w * 16 + (l >> 2));
    const _Float16* aH = APh + (size_t)(row0 + r_l) * 1024 + kc * 8;
    const _Float16* aM = APm + (size_t)(row0 + r_l) * 1024 + kc * 8;
    const _Float16* bH = BPh + (size_t)(col0 + (w * 32 + (l >> 2))) * 1024 + kc * 8;
    const _Float16* bM = BPm + (size_t)(col0 + (w * 32 + (l >> 2))) * 1024 + kc * 8;

    const int kcsel = l >> 4, rsel = l & 15;
    const int swz  = (kcsel ^ ((rsel >> 1) & 3)) * 16;
    const int offA = (wr * (BM / 2) + rsel) * 64 + swz;
    const int offB = (wc * 64 + rsel) * 64 + swz;

#define STG(buf, kk) do {                                        \
        char* dst = smem + (buf) * BUF;                          \
        if (BM == 128) {                                         \
            char* da = dst + w * 2048;                           \
            gload_lds16(aH + (kk),         da);                  \
            gload_lds16(aH + (kk) + 16384, da + 1024);           \
            gload_lds16(aM + (kk),         da + ASLAB);          \
            gload_lds16(aM + (kk) + 16384, da + ASLAB + 1024);   \
        } else {                                                 \
            char* da = dst + w * 1024;                           \
            gload_lds16(aH + (kk), da);                          \
            gload_lds16(aM + (kk), da + ASLAB);                  \
        }                                                        \
        char* db = dst + 2 * ASLAB + w * 2048;                   \
        gload_lds16(bH + (kk),         db);                      \
        gload_lds16(bH + (kk) + 16384, db + 1024);               \
        gload_lds16(bM + (kk),         db + 8192);               \
        gload_lds16(bM + (kk) + 16384, db + 9216);               \
    } while (0)

#define CMP(buf) do {                                                           \
        const char* sb = smem + (buf) * BUF;                                    \
        f16x8 ah[MM], am[MM], bh[4], bm[4];                                     \
        _Pragma("unroll")                                                       \
        for (int mm = 0; mm < MM; mm++) {                                       \
            ah[mm] = *(const f16x8*)(sb + offA + mm * 1024);                    \
            am[mm] = *(const f16x8*)(sb + ASLAB + offA + mm * 1024);            \
        }                                                                       \
        _Pragma("unroll")                                                       \
        for (int nn = 0; nn < 4; nn++) {                                        \
            bh[nn] = *(const f16x8*)(sb + 2 * ASLAB + offB + nn * 1024);        \
            bm[nn] = *(const f16x8*)(sb + 2 * ASLAB + 8192 + offB + nn * 1024); \
        }                                                                       \
        _Pragma("unroll")                                                       \
        for (int mm = 0; mm < MM; mm++) {                                       \
            _Pragma("unroll")                                                   \
            for (int nn = 0; nn < 4; nn++) {                                    \
                f32x4 cc = acc[mm][nn];                                         \
                cc = __builtin_amdgcn_mfma_f32_16x16x32_f16(am[mm], bh[nn], cc, 0, 0, 0); \
                cc = __builtin_amdgcn_mfma_f32_16x16x32_f16(ah[mm], bm[nn], cc, 0, 0, 0); \
                cc = __builtin_amdgcn_mfma_f32_16x16x32_f16(ah[mm], bh[nn], cc, 0, 0, 0); \
                acc[mm][nn] = cc;                                               \
            }                                                                   \
        }                                                                       \
    } while (0)

    STG(0, 0);
    __syncthreads();
    int cur = 0;
    #pragma unroll 1
    for (int ks = 0; ks < 31; ks++) {
        STG(cur ^ 1, (ks + 1) * 32);
        CMP(cur);
        __syncthreads();
        cur ^= 1;
    }
    CMP(cur);
#undef STG
#undef CMP

    const int r_in = (l >> 4) * 4;
    const int c_in = l & 15;
    #pragma unroll
    for (int mm = 0; mm < MM; mm++) {
        #pragma unroll
        for (int nn = 0; nn < 4; nn++) {
            int col = col0 + wc * 64 + nn * 16 + c_in;
            float bv = bias[col];
            #pragma unroll
            for (int j = 0; j < 4; j++) {
                int row = row0 + wr * (BM / 2) + mm * 16 + r_in + j;
                float v = acc[mm][nn][j] + bv;
                if (RELU) v = fmaxf(v, 0.f);
                size_t o = (size_t)row * ldc + col;
                if (WF32) C[o] = v;
                if (WPL) {
                    _Float16 h, m; split2(v, h, m);
                    Ph[o] = h; Pm[o] = m;
                }
            }
        }
    }
}

// standalone GEMM kernel (256 threads)
template <int BM, int RELU, int WF32, int WPL>
__global__ __launch_bounds__(256) void k_gemm2(
    const _Float16* __restrict__ APh, const _Float16* __restrict__ APm,
    const _Float16* __restrict__ BPh, const _Float16* __restrict__ BPm,
    const float* __restrict__ bias,
    float* __restrict__ C, long ldc,
    _Float16* __restrict__ Ph, _Float16* __restrict__ Pm) {
    __shared__ __align__(16) char smem[(BM * 64 * 2 + 16384) * 2];
    gemm_core<BM, RELU, WF32, WPL>(APh, APm, BPh, BPm, bias, C, ldc, Ph, Pm,
                                   blockIdx.x * BM, blockIdx.y * 128, smem);
}

// grouped pair: two independent 128x128-tile GEMMs in one dispatch
struct GemmP {
    const _Float16* APh; const _Float16* APm;
    const _Float16* BPh; const _Float16* BPm;
    const float* bias; float* C; long ldc;
};
__global__ __launch_bounds__(256) void k_gemm_pair(GemmP p0, int n0, int gw0,
                                                   GemmP p1, int gw1) {
    __shared__ __align__(16) char smem[65536];
    int id = blockIdx.x;
    if (id < n0) {
        gemm_core<128, 0, 1, 0>(p0.APh, p0.APm, p0.BPh, p0.BPm, p0.bias, p0.C, p0.ldc,
                                nullptr, nullptr, (id % gw0) * 128, (id / gw0) * 128, smem);
    } else {
        id -= n0;
        gemm_core<128, 0, 1, 0>(p1.APh, p1.APm, p1.BPh, p1.BPm, p1.bias, p1.C, p1.ldc,
                                nullptr, nullptr, (id % gw1) * 128, (id / gw1) * 128, smem);
    }
}

// =====================================================================
// FUSED: LN(qkv) + attention (2 heads/iter) + m = LN(m + att).
// m is planes-only (Ph/Pm in & out). grid = BATCH, 512 threads.
// =====================================================================
__global__ __launch_bounds__(512) void k_ln_attn_addln1(
    const float* __restrict__ qkv,
    const float* __restrict__ gq, const float* __restrict__ bq,   // [9][3072]
    _Float16* __restrict__ Ph, _Float16* __restrict__ Pm,
    const float* __restrict__ g1, const float* __restrict__ b1) { // [9216]
    __shared__ float att_out[9][1024];
    __shared__ float qs[2][9][128], ks[2][9][128], vs[2][9][128];
    __shared__ float att[2][9][12];
    __shared__ float red[16];
    const int tid = threadIdx.x;
    const int b   = blockIdx.x;
    const float* Q = qkv + (size_t)b * 27648;

    float s = 0.f, ss = 0.f;
    for (int i = tid * 4; i < 27648; i += 2048) {
        f32x4 v = *(const f32x4*)(Q + i);
        s  += v[0] + v[1] + v[2] + v[3];
        ss += v[0]*v[0] + v[1]*v[1] + v[2]*v[2] + v[3]*v[3];
    }
    bred8(s, ss, red, tid);
    const float invn = 1.f / 27648.f;
    const float mean = s * invn;
    const float rstd = rsqrtf(ss * invn - mean * mean + 1e-5f);
    const float scale = 0.08838834764831845f;  // 128^-0.5

    for (int h0 = 0; h0 < 8; h0 += 2) {
        __syncthreads();
        for (int i = tid; i < 2304; i += 512) {
            int hh = i / 1152, rem = i - hh * 1152;
            int sx = rem >> 7, d = rem & 127;
            int gb = sx * 3072 + (h0 + hh) * 384 + d;
            qs[hh][sx][d] = ((Q[gb]       - mean) * rstd * gq[gb]       + bq[gb])       * scale;
            ks[hh][sx][d] =  (Q[gb + 128] - mean) * rstd * gq[gb + 128] + bq[gb + 128];
            vs[hh][sx][d] =  (Q[gb + 256] - mean) * rstd * gq[gb + 256] + bq[gb + 256];
        }
        __syncthreads();
        for (int g = tid >> 2; g < 162; g += 128) {
            int hh = g / 81, r = g - hh * 81;
            int qi = r / 9, ki = r - qi * 9;
            const float* qp = qs[hh][qi];
            const float* kp = ks[hh][ki];
            float s4 = 0.f;
            for (int d = tid & 3; d < 128; d += 4) s4 += qp[d] * kp[d];
            s4 += __shfl_xor(s4, 1);
            s4 += __shfl_xor(s4, 2);
            if ((tid & 3) == 0) att[hh][qi][ki] = s4;
        }
        __syncthreads();
        if (tid < 18) {
            int hh = tid / 9, qi = tid - hh * 9;
            float mx = att[hh][qi][0];
            #pragma unroll
            for (int j = 1; j < 9; j++) mx = fmaxf(mx, att[hh][qi][j]);
            float e[9]; float sum = 0.f;
            #pragma unroll
            for (int j = 0; j < 9; j++) { e[j] = expf(att[hh][qi][j] - mx); sum += e[j]; }
            float inv = 1.f / sum;
            #pragma unroll
            for (int j = 0; j < 9; j++) att[hh][qi][j] = e[j] * inv;
        }
        __syncthreads();
        for (int i = tid; i < 2304; i += 512) {
            int hh = i / 1152, rem = i - hh * 1152;
            int sx = rem >> 7, d = rem & 127;
            float ov = 0.f;
            #pragma unroll
            for (int k = 0; k < 9; k++) ov += att[hh][sx][k] * vs[hh][k][d];
            att_out[sx][(h0 + hh) * 128 + d] = ov;
        }
    }
    __syncthreads();

    // ---- m = LN(m + att_out); m reconstructed from planes; emit planes ----
    float* X = &att_out[0][0];
    const size_t pb = (size_t)b * 9216;
    s = 0.f; ss = 0.f;
    for (int i = tid * 4; i < 9216; i += 2048) {
        f16x4 hp = *(const f16x4*)(Ph + pb + i);
        f16x4 mp = *(const f16x4*)(Pm + pb + i);
        f32x4 v;
        #pragma unroll
        for (int j = 0; j < 4; j++) v[j] = (float)hp[j] + (float)mp[j];
        v += *(const f32x4*)(X + i);
        *(f32x4*)(X + i) = v;
        s  += v[0] + v[1] + v[2] + v[3];
        ss += v[0]*v[0] + v[1]*v[1] + v[2]*v[2] + v[3]*v[3];
    }
    bred8(s, ss, red, tid);
    const float invn2 = 1.f / 9216.f;
    const float mean2 = s * invn2;
    const float rstd2 = rsqrtf(ss * invn2 - mean2 * mean2 + 1e-5f);
    for (int i = tid * 4; i < 9216; i += 2048) {
        f32x4 v  = *(const f32x4*)(X + i);
        f32x4 gg = *(const f32x4*)(g1 + i);
        f32x4 bv = *(const f32x4*)(b1 + i);
        v = (v - mean2) * rstd2 * gg + bv;
        f16x4 h, m;
        #pragma unroll
        for (int j = 0; j < 4; j++) { _Float16 hh, mm; split2(v[j], hh, mm); h[j] = hh; m[j] = mm; }
        *(f16x4*)(Ph + pb + i) = h;
        *(f16x4*)(Pm + pb + i) = m;
    }
}

// =====================================================================
// FUSED: m = LN(m + h2); gate; write out_t, mem, next-step planes,
// tanh planes. m planes-only. grid = BATCH, 512 threads.
// =====================================================================
__global__ __launch_bounds__(512) void k_addln2_gate(
    const float* __restrict__ h2,
    const float* __restrict__ g2, const float* __restrict__ b2,
    const float* __restrict__ gmem,
    const float* __restrict__ ginp, long ginp_stride,
    const float* __restrict__ inp_next, long inp_stride,
    const float* __restrict__ fbp, const float* __restrict__ ibp,
    float* __restrict__ mem, float* __restrict__ outp,
    _Float16* __restrict__ Ph, _Float16* __restrict__ Pm,
    _Float16* __restrict__ Th, _Float16* __restrict__ Tm) {
    __shared__ float xs[9216];
    __shared__ float red[16];
    const int tid = threadIdx.x, b = blockIdx.x;
    const size_t pb = (size_t)b * 9216;
    const float* H = h2 + pb;
    float s = 0.f, ss = 0.f;
    for (int i = tid * 4; i < 9216; i += 2048) {
        f16x4 hp = *(const f16x4*)(Ph + pb + i);
        f16x4 mp = *(const f16x4*)(Pm + pb + i);
        f32x4 v;
        #pragma unroll
        for (int j = 0; j < 4; j++) v[j] = (float)hp[j] + (float)mp[j];
        v += *(const f32x4*)(H + i);
        *(f32x4*)(xs + i) = v;
        s  += v[0] + v[1] + v[2] + v[3];
        ss += v[0]*v[0] + v[1]*v[1] + v[2]*v[2] + v[3]*v[3];
    }
    bred8(s, ss, red, tid);
    const float invn = 1.f / 9216.f;
    const float mean = s * invn;
    const float rstd = rsqrtf(ss * invn - mean * mean + 1e-5f);
    const float FB = *fbp, IB = *ibp;

    for (int i = tid * 4; i < 8192; i += 2048) {
        int sx = i >> 10, c = i & 1023;
        size_t gr = (size_t)(b * 8 + sx);
        f32x4 x   = *(const f32x4*)(xs + i);
        f32x4 gm1 = *(const f32x4*)(gmem + gr * 2048 + c);
        f32x4 gm2 = *(const f32x4*)(gmem + gr * 2048 + 1024 + c);
        f32x4 gi1 = *(const f32x4*)(ginp + (size_t)b * ginp_stride + c);
        f32x4 gi2 = *(const f32x4*)(ginp + (size_t)b * ginp_stride + 1024 + c);
        f32x4 old = *(const f32x4*)(mem + gr * 1024 + c);
        f32x4 gg  = *(const f32x4*)(g2 + i);
        f32x4 bb  = *(const f32x4*)(b2 + i);
        f32x4 o;
        f16x4 oh, om, th, tm;
        #pragma unroll
        for (int j = 0; j < 4; j++) {
            float cand = (x[j] - mean) * rstd * gg[j] + bb[j];
            float igv = sigf(gm1[j] + gi1[j] + IB);
            float fgv = sigf(gm2[j] + gi2[j] + FB);
            o[j] = igv * tanhf(cand) + fgv * old[j];
            _Float16 hh, mm; split2(o[j], hh, mm); oh[j] = hh; om[j] = mm;
            float tv = tanhf(o[j]);
            split2(tv, hh, mm); th[j] = hh; tm[j] = mm;
        }
        *(f32x4*)(mem + gr * 1024 + c)         = o;
        *(f32x4*)(outp + (size_t)b * 8192 + i) = o;
        *(f16x4*)(Ph + pb + i) = oh;
        *(f16x4*)(Pm + pb + i) = om;
        size_t to = (size_t)b * 8192 + i;
        *(f16x4*)(Th + to) = th;
        *(f16x4*)(Tm + to) = tm;
    }
    if (inp_next != nullptr && tid < 256) {
        int c = tid * 4;
        f32x4 v = *(const f32x4*)(inp_next + (size_t)b * inp_stride + c);
        f16x4 h, m;
        #pragma unroll
        for (int j = 0; j < 4; j++) { _Float16 hh, mm; split2(v[j], hh, mm); h[j] = hh; m[j] = mm; }
        *(f16x4*)(Ph + pb + 8192 + c) = h;
        *(f16x4*)(Pm + pb + 8192 + c) = m;
    }
}

// =====================================================================
// host launcher
// =====================================================================
extern "C" void kernel_launch(void* const* d_in, const int* in_sizes, int n_in,
                              void* d_out, int out_size, void* d_ws, size_t ws_size,
                              hipStream_t stream) {
    const float* inputs = (const float*)d_in[0];
    const float* memory = (const float*)d_in[1];
    const float* W_qkv  = (const float*)d_in[2];
    const float* b_qkv  = (const float*)d_in[3];
    const float* g_qln  = (const float*)d_in[4];
    const float* b_qln  = (const float*)d_in[5];
    const float* W_mlp  = (const float*)d_in[6];
    const float* b_mlp  = (const float*)d_in[7];
    const float* g_ln1  = (const float*)d_in[8];
    const float* b_ln1  = (const float*)d_in[9];
    const float* g_ln2  = (const float*)d_in[10];
    const float* b_ln2  = (const float*)d_in[11];
    const float* W_in   = (const float*)d_in[12];
    const float* b_in   = (const float*)d_in[13];
    const float* W_ig   = (const float*)d_in[14];
    const float* b_ig   = (const float*)d_in[15];
    const float* W_mg   = (const float*)d_in[16];
    const float* b_mg   = (const float*)d_in[17];
    const float* fb     = (const float*)d_in[18];
    const float* ib     = (const float*)d_in[19];
    float* out = (float*)d_out;

    char* ws = (char*)d_ws;
    size_t off = 0;
    auto alloc = [&](size_t bytes) -> char* {
        char* p = ws + off;
        off += (bytes + 255) & ~(size_t)255;
        return p;
    };
    const size_t NEin = (size_t)1024*1024, NEqkv = (size_t)3072*1024,
                 NEmlp = (size_t)1024*1024, NEig = (size_t)2048*1024, NEmg = (size_t)2048*1024;
    _Float16* WinP  = (_Float16*)alloc(NEin  * 2 * 2);
    _Float16* WqkvP = (_Float16*)alloc(NEqkv * 2 * 2);
    _Float16* WmlpP = (_Float16*)alloc(NEmlp * 2 * 2);
    _Float16* WigP  = (_Float16*)alloc(NEig  * 2 * 2);
    _Float16* WmgP  = (_Float16*)alloc(NEmg  * 2 * 2);

    float*    mem_ws = (float*)alloc((size_t)2048 * 1024 * 4);
    _Float16* mbufP  = (_Float16*)alloc((size_t)2304 * 1024 * 2 * 2);
    float*    qkvbuf = (float*)alloc((size_t)2304 * 3072 * 4);
    float*    gmemb  = (float*)alloc((size_t)2048 * 2048 * 4);
    _Float16* h1P    = (_Float16*)alloc((size_t)2304 * 1024 * 2 * 2);
    float*    h2buf  = (float*)alloc((size_t)2304 * 1024 * 4);
    _Float16* tanhP  = (_Float16*)alloc((size_t)2048 * 1024 * 2 * 2);

    const size_t NEm   = (size_t)2304 * 1024;
    const size_t NEt   = (size_t)2048 * 1024;
    const size_t NEbig = (size_t)8192 * 1024;

    size_t big_bytes = NEbig*2*2 + NEbig*4 + NEbig*2*2 + (size_t)8192*2048*4 + 8192;
    bool big = (ws_size >= off + big_bytes);

    dim3 tb(32, 8);
    k_transpose_split2<<<dim3(32, 32), tb, 0, stream>>>(W_in,  WinP,  WinP + NEin,  1024, 1024);
    k_transpose_split2<<<dim3(32, 96), tb, 0, stream>>>(W_qkv, WqkvP, WqkvP + NEqkv, 3072, 1024);
    k_transpose_split2<<<dim3(32, 32), tb, 0, stream>>>(W_mlp, WmlpP, WmlpP + NEmlp, 1024, 1024);
    k_transpose_split2<<<dim3(32, 64), tb, 0, stream>>>(W_ig,  WigP,  WigP + NEig,  2048, 1024);
    k_transpose_split2<<<dim3(32, 64), tb, 0, stream>>>(W_mg,  WmgP,  WmgP + NEmg,  2048, 1024);

    GemmP pq = { mbufP, mbufP + NEm, WqkvP, WqkvP + NEqkv, b_qkv, qkvbuf, 3072 };
    GemmP pg = { tanhP, tanhP + NEt, WmgP,  WmgP  + NEmg,  b_mg,  gmemb,  2048 };

    if (big) {
        _Float16* inputsP  = (_Float16*)alloc(NEbig * 2 * 2);
        float*    inp_all  = (float*)alloc(NEbig * 4);
        _Float16* inp_allP = (_Float16*)alloc(NEbig * 2 * 2);
        float*    ginp_all = (float*)alloc((size_t)8192 * 2048 * 4);

        k_split2_rows<<<8192, 256, 0, stream>>>(inputs, 1024, inputsP, inputsP + NEbig, 8192 * 256);
        k_gemm2<128,0,1,1><<<dim3(64, 8), 256, 0, stream>>>(inputsP, inputsP + NEbig,
            WinP, WinP + NEin, b_in, inp_all, 1024, inp_allP, inp_allP + NEbig);
        k_gemm2<128,0,1,0><<<dim3(64, 16), 256, 0, stream>>>(inp_allP, inp_allP + NEbig,
            WigP, WigP + NEig, b_ig, ginp_all, 2048, nullptr, nullptr);
        k_prep0<<<2304, 256, 0, stream>>>(mbufP, mbufP + NEm, memory, mem_ws,
                                          tanhP, tanhP + NEt, inp_all, (long)SEQT * 1024);

        for (int t = 0; t < SEQT; t++) {
            k_gemm_pair<<<688, 256, 0, stream>>>(pq, 432, 18, pg, 16);
            k_ln_attn_addln1<<<BATCH, 512, 0, stream>>>(qkvbuf, g_qln, b_qln,
                mbufP, mbufP + NEm, g_ln1, b_ln1);
            k_gemm2<64,1,0,1><<<dim3(36, 8), 256, 0, stream>>>(mbufP, mbufP + NEm,
                WmlpP, WmlpP + NEmlp, b_mlp, nullptr, 1024, h1P, h1P + NEm);
            k_gemm2<64,1,1,0><<<dim3(36, 8), 256, 0, stream>>>(h1P, h1P + NEm,
                WmlpP, WmlpP + NEmlp, b_mlp, h2buf, 1024, nullptr, nullptr);
            const float* inp_next = (t + 1 < SEQT) ? (inp_all + (size_t)(t + 1) * 1024) : nullptr;
            k_addln2_gate<<<BATCH, 512, 0, stream>>>(h2buf, g_ln2, b_ln2,
                gmemb, ginp_all + (size_t)t * 2048, (long)SEQT * 2048,
                inp_next, (long)SEQT * 1024, fb, ib, mem_ws,
                out + (size_t)t * (BATCH * 8192),
                mbufP, mbufP + NEm, tanhP, tanhP + NEt);
        }
    } else {
        const size_t NEs = (size_t)256 * 1024;
        _Float16* stepP  = (_Float16*)alloc(NEs * 2 * 2);
        float*    inpA   = (float*)alloc(NEs * 4);
        _Float16* inpAP  = (_Float16*)alloc(NEs * 2 * 2);
        float*    inpB   = (float*)alloc(NEs * 4);
        _Float16* inpBP  = (_Float16*)alloc(NEs * 2 * 2);
        float*    ginpA  = (float*)alloc((size_t)256 * 2048 * 4);
        float*    ginpB  = (float*)alloc((size_t)256 * 2048 * 4);

        k_split2_rows<<<256, 256, 0, stream>>>(inputs, (long)SEQT * 1024, stepP, stepP + NEs, 256 * 256);
        k_gemm2<128,0,1,1><<<dim3(2, 8), 256, 0, stream>>>(stepP, stepP + NEs,
            WinP, WinP + NEin, b_in, inpA, 1024, inpAP, inpAP + NEs);
        k_gemm2<128,0,1,0><<<dim3(2, 16), 256, 0, stream>>>(inpAP, inpAP + NEs,
            WigP, WigP + NEig, b_ig, ginpA, 2048, nullptr, nullptr);
        k_prep0<<<2304, 256, 0, stream>>>(mbufP, mbufP + NEm, memory, mem_ws,
                                          tanhP, tanhP + NEt, inpA, 1024);

        float *ci = inpA, *cg = ginpA, *ni = inpB, *ng = ginpB;
        _Float16* niP = inpBP;
        _Float16* ciP = inpAP;
        for (int t = 0; t < SEQT; t++) {
            k_gemm_pair<<<688, 256, 0, stream>>>(pq, 432, 18, pg, 16);
            k_ln_attn_addln1<<<BATCH, 512, 0, stream>>>(qkvbuf, g_qln, b_qln,
                mbufP, mbufP + NEm, g_ln1, b_ln1);
            k_gemm2<64,1,0,1><<<dim3(36, 8), 256, 0, stream>>>(mbufP, mbufP + NEm,
                WmlpP, WmlpP + NEmlp, b_mlp, nullptr, 1024, h1P, h1P + NEm);
            k_gemm2<64,1,1,0><<<dim3(36, 8), 256, 0, stream>>>(h1P, h1P + NEm,
                WmlpP, WmlpP + NEmlp, b_mlp, h2buf, 1024, nullptr, nullptr);
            const float* inp_next = nullptr;
            if (t + 1 < SEQT) {
                k_split2_rows<<<256, 256, 0, stream>>>(inputs + (size_t)(t + 1) * 1024,
                    (long)SEQT * 1024, stepP, stepP + NEs, 256 * 256);
                k_gemm2<128,0,1,1><<<dim3(2, 8), 256, 0, stream>>>(stepP, stepP + NEs,
                    WinP, WinP + NEin, b_in, ni, 1024, niP, niP + NEs);
                k_gemm2<128,0,1,0><<<dim3(2, 16), 256, 0, stream>>>(niP, niP + NEs,
                    WigP, WigP + NEig, b_ig, ng, 2048, nullptr, nullptr);
                inp_next = ni;
            }
            k_addln2_gate<<<BATCH, 512, 0, stream>>>(h2buf, g_ln2, b_ln2,
                gmemb, cg, 2048, inp_next, 1024, fb, ib, mem_ws,
                out + (size_t)t * (BATCH * 8192),
                mbufP, mbufP + NEm, tanhP, tanhP + NEt);
            { float* tmp = ci; ci = ni; ni = tmp; }
            { float* tmp = cg; cg = ng; ng = tmp; }
            { _Float16* tmp = ciP; ciP = niP; niP = tmp; }
        }
    }
    k_copy<<<2048, 256, 0, stream>>>(mem_ws, out + (size_t)SEQT * BATCH * 8192, 524288);
}